// Round 2
// baseline (2585.754 us; speedup 1.0000x reference)
//
#include <hip/hip_runtime.h>
#include <hip/hip_bf16.h>

// Problem constants (match reference)
constexpr int Bc = 4, Tc = 4096, Dc = 1024, Hc = 16, Ec = 8;
constexpr int SPANc = 64, NSc = 64, HDc = 64, GHc = 128;
#define FINF_MIN (-3.402823466e38f)

// ---------------------------------------------------------------------------
// Kernel 1: per-span gating (masked mean-pool -> MLP -> top-2 softmax)
// Grid: B*NS blocks of 256 threads. Output: eidx[span*2], egw[span*2] in ws.
// ---------------------------------------------------------------------------
__global__ __launch_bounds__(256) void gate_kernel(
    const float* __restrict__ x, const int* __restrict__ mask,
    const float* __restrict__ w1, const float* __restrict__ b1,
    const float* __restrict__ w2, const float* __restrict__ b2,
    int* __restrict__ eidx, float* __restrict__ egw)
{
  const int span = blockIdx.x;            // 0..255
  const int b = span / NSc, s = span % NSc;
  const int tid = threadIdx.x;

  __shared__ float mv[SPANc];
  __shared__ float msum_s;
  __shared__ float pooled[Dc];
  __shared__ float hbuf[GHc];
  __shared__ float logits[Ec];

  if (tid < SPANc) mv[tid] = (float)mask[(size_t)b * Tc + s * SPANc + tid];
  __syncthreads();
  if (tid == 0) {
    float ms = 0.f;
    for (int l = 0; l < SPANc; ++l) ms += mv[l];
    msum_s = fmaxf(ms, 1e-9f);
  }
  __syncthreads();

  {  // masked mean pool: each thread owns 4 columns
    const int c0 = tid * 4;
    float a0 = 0.f, a1 = 0.f, a2 = 0.f, a3 = 0.f;
    const float* xb = x + ((size_t)b * Tc + s * SPANc) * Dc + c0;
    for (int l = 0; l < SPANc; ++l) {
      const float m = mv[l];
      const float4 v = *reinterpret_cast<const float4*>(xb + (size_t)l * Dc);
      a0 += v.x * m; a1 += v.y * m; a2 += v.z * m; a3 += v.w * m;
    }
    const float inv = 1.f / msum_s;
    pooled[c0 + 0] = a0 * inv; pooled[c0 + 1] = a1 * inv;
    pooled[c0 + 2] = a2 * inv; pooled[c0 + 3] = a3 * inv;
  }
  __syncthreads();

  if (tid < GHc) {  // hidden layer
    const float* wr = w1 + (size_t)tid * Dc;
    float acc = b1[tid];
    for (int c = 0; c < Dc; c += 4) {
      const float4 w = *reinterpret_cast<const float4*>(wr + c);
      acc += pooled[c] * w.x + pooled[c + 1] * w.y + pooled[c + 2] * w.z + pooled[c + 3] * w.w;
    }
    hbuf[tid] = fmaxf(acc, 0.f);
  }
  __syncthreads();

  if (tid < Ec) {  // logits
    const float* wr = w2 + tid * GHc;
    float acc = b2[tid];
    for (int j = 0; j < GHc; ++j) acc += hbuf[j] * wr[j];
    logits[tid] = acc;
  }
  __syncthreads();

  if (tid == 0) {  // top-2 (ties -> lowest index, matching lax.top_k) + softmax
    int e0 = 0; float v0 = logits[0];
    for (int e = 1; e < Ec; ++e) { if (logits[e] > v0) { v0 = logits[e]; e0 = e; } }
    int e1 = (e0 == 0) ? 1 : 0; float v1 = logits[e1];
    for (int e = 0; e < Ec; ++e) {
      if (e == e0 || e == e1) continue;
      if (logits[e] > v1) { v1 = logits[e]; e1 = e; }
    }
    const float ex = expf(v1 - v0);               // v0 >= v1, stable
    const float den = 1.f + ex;
    eidx[span * 2 + 0] = e0; eidx[span * 2 + 1] = e1;
    egw[span * 2 + 0] = 1.f / den; egw[span * 2 + 1] = ex / den;
  }
}

// ---------------------------------------------------------------------------
// Kernel 2: fused per-(b, span, head) block.
//   - Combines the 2 selected experts' W tiles in LDS (halves GEMM FLOPs)
//   - Computes Q/K/V 64x64 head slices (K=1024) in fp32
//   - 64x64 softmax attention fully in LDS, writes output slice
// Grid: (H, NS, B) blocks of 256 threads; 64 KB LDS.
// ---------------------------------------------------------------------------
__global__ __launch_bounds__(256) void moe_attn_kernel(
    const float* __restrict__ x, const int* __restrict__ mask,
    const float* __restrict__ Wq, const float* __restrict__ Wk,
    const float* __restrict__ Wv,
    const int* __restrict__ eidx, const float* __restrict__ egw,
    float* __restrict__ out)
{
  const int h = blockIdx.x;
  const int s = blockIdx.y;
  const int b = blockIdx.z;
  const int span = b * NSc + s;
  const int tid = threadIdx.x;
  const int tx = tid & 15;       // output col group (f = tx*4+j)
  const int ty = tid >> 4;       // output row group (l = ty*4+i)

  __shared__ float xsT[32][64];  // k-major x tile  (xsT[kk][l])
  __shared__ float wsT[32][64];  // k-major combined W tile (wsT[kk][f])
  __shared__ float qs[64][64];   // Q slice; later reused for P (probs)
  __shared__ float ks[64][64];
  __shared__ float vs[64][64];

  const int e0 = eidx[span * 2 + 0];
  const int e1 = eidx[span * 2 + 1];
  const float g0 = egw[span * 2 + 0];
  const float g1 = egw[span * 2 + 1];

  const float* xb = x + ((size_t)b * Tc + s * SPANc) * Dc;  // 64 x 1024
  const int lrow = tid >> 2;          // 0..63 (row of the staged tile)
  const int kk0 = (tid & 3) * 8;      // 0,8,16,24

  for (int p = 0; p < 3; ++p) {
    const float* Wp = (p == 0) ? Wq : (p == 1) ? Wk : Wv;
    float* dp = (p == 0) ? &qs[0][0] : (p == 1) ? &ks[0][0] : &vs[0][0];
    const float* W0 = Wp + ((size_t)e0 * Dc + h * HDc) * Dc;
    const float* W1 = Wp + ((size_t)e1 * Dc + h * HDc) * Dc;
    float acc[4][4] = {{0.f, 0.f, 0.f, 0.f}, {0.f, 0.f, 0.f, 0.f},
                       {0.f, 0.f, 0.f, 0.f}, {0.f, 0.f, 0.f, 0.f}};
    for (int t = 0; t < Dc / 32; ++t) {
      const int k0 = t * 32;
      // stage x tile (transposed) + combined expert-W tile
      {
        const float* sx = xb + (size_t)lrow * Dc + k0 + kk0;
        const float4 xv0 = *reinterpret_cast<const float4*>(sx);
        const float4 xv1 = *reinterpret_cast<const float4*>(sx + 4);
        const float* sw0 = W0 + (size_t)lrow * Dc + k0 + kk0;
        const float* sw1 = W1 + (size_t)lrow * Dc + k0 + kk0;
        const float4 wa0 = *reinterpret_cast<const float4*>(sw0);
        const float4 wa1 = *reinterpret_cast<const float4*>(sw0 + 4);
        const float4 wb0 = *reinterpret_cast<const float4*>(sw1);
        const float4 wb1 = *reinterpret_cast<const float4*>(sw1 + 4);
        xsT[kk0 + 0][lrow] = xv0.x; xsT[kk0 + 1][lrow] = xv0.y;
        xsT[kk0 + 2][lrow] = xv0.z; xsT[kk0 + 3][lrow] = xv0.w;
        xsT[kk0 + 4][lrow] = xv1.x; xsT[kk0 + 5][lrow] = xv1.y;
        xsT[kk0 + 6][lrow] = xv1.z; xsT[kk0 + 7][lrow] = xv1.w;
        wsT[kk0 + 0][lrow] = g0 * wa0.x + g1 * wb0.x;
        wsT[kk0 + 1][lrow] = g0 * wa0.y + g1 * wb0.y;
        wsT[kk0 + 2][lrow] = g0 * wa0.z + g1 * wb0.z;
        wsT[kk0 + 3][lrow] = g0 * wa0.w + g1 * wb0.w;
        wsT[kk0 + 4][lrow] = g0 * wa1.x + g1 * wb1.x;
        wsT[kk0 + 5][lrow] = g0 * wa1.y + g1 * wb1.y;
        wsT[kk0 + 6][lrow] = g0 * wa1.z + g1 * wb1.z;
        wsT[kk0 + 7][lrow] = g0 * wa1.w + g1 * wb1.w;
      }
      __syncthreads();
#pragma unroll
      for (int kk = 0; kk < 32; ++kk) {
        const float4 av = *reinterpret_cast<const float4*>(&xsT[kk][ty * 4]);
        const float4 wv = *reinterpret_cast<const float4*>(&wsT[kk][tx * 4]);
        acc[0][0] += av.x * wv.x; acc[0][1] += av.x * wv.y;
        acc[0][2] += av.x * wv.z; acc[0][3] += av.x * wv.w;
        acc[1][0] += av.y * wv.x; acc[1][1] += av.y * wv.y;
        acc[1][2] += av.y * wv.z; acc[1][3] += av.y * wv.w;
        acc[2][0] += av.z * wv.x; acc[2][1] += av.z * wv.y;
        acc[2][2] += av.z * wv.z; acc[2][3] += av.z * wv.w;
        acc[3][0] += av.w * wv.x; acc[3][1] += av.w * wv.y;
        acc[3][2] += av.w * wv.z; acc[3][3] += av.w * wv.w;
      }
      __syncthreads();
    }
#pragma unroll
    for (int i = 0; i < 4; ++i) {
      *reinterpret_cast<float4*>(dp + (size_t)(ty * 4 + i) * 64 + tx * 4) =
          make_float4(acc[i][0], acc[i][1], acc[i][2], acc[i][3]);
    }
    __syncthreads();
  }

  // ---- scores = Q K^T / sqrt(hd), masked ----
  bool kvalid[4];
#pragma unroll
  for (int j = 0; j < 4; ++j)
    kvalid[j] = mask[(size_t)b * Tc + s * SPANc + tx * 4 + j] != 0;

  float sacc[4][4] = {{0.f, 0.f, 0.f, 0.f}, {0.f, 0.f, 0.f, 0.f},
                      {0.f, 0.f, 0.f, 0.f}, {0.f, 0.f, 0.f, 0.f}};
  for (int dd = 0; dd < 64; ++dd) {
    const int d = (dd + tid) & 63;   // staggered to avoid bank conflicts
    const float a0 = qs[ty * 4 + 0][d], a1 = qs[ty * 4 + 1][d];
    const float a2 = qs[ty * 4 + 2][d], a3 = qs[ty * 4 + 3][d];
    const float b0 = ks[tx * 4 + 0][d], b1v = ks[tx * 4 + 1][d];
    const float b2v = ks[tx * 4 + 2][d], b3 = ks[tx * 4 + 3][d];
    sacc[0][0] += a0 * b0; sacc[0][1] += a0 * b1v; sacc[0][2] += a0 * b2v; sacc[0][3] += a0 * b3;
    sacc[1][0] += a1 * b0; sacc[1][1] += a1 * b1v; sacc[1][2] += a1 * b2v; sacc[1][3] += a1 * b3;
    sacc[2][0] += a2 * b0; sacc[2][1] += a2 * b1v; sacc[2][2] += a2 * b2v; sacc[2][3] += a2 * b3;
    sacc[3][0] += a3 * b0; sacc[3][1] += a3 * b1v; sacc[3][2] += a3 * b2v; sacc[3][3] += a3 * b3;
  }
  __syncthreads();  // done reading qs; safe to overwrite with P
#pragma unroll
  for (int i = 0; i < 4; ++i)
#pragma unroll
    for (int j = 0; j < 4; ++j)
      qs[ty * 4 + i][tx * 4 + j] = kvalid[j] ? sacc[i][j] * 0.125f : FINF_MIN;
  __syncthreads();

  // ---- row softmax (64 rows by the first 64 lanes, staggered column order) ----
  if (tid < 64) {
    const int l = tid;
    float mx = FINF_MIN;
    for (int mm = 0; mm < 64; ++mm) {
      const int m = (mm + tid) & 63;
      mx = fmaxf(mx, qs[l][m]);
    }
    float sum = 0.f;
    for (int mm = 0; mm < 64; ++mm) {
      const int m = (mm + tid) & 63;
      const float e = expf(qs[l][m] - mx);
      qs[l][m] = e;
      sum += e;
    }
    const float inv = 1.f / sum;
    for (int mm = 0; mm < 64; ++mm) {
      const int m = (mm + tid) & 63;
      qs[l][m] *= inv;
    }
  }
  __syncthreads();

  // ---- ctx = P V ----
  float cacc[4][4] = {{0.f, 0.f, 0.f, 0.f}, {0.f, 0.f, 0.f, 0.f},
                      {0.f, 0.f, 0.f, 0.f}, {0.f, 0.f, 0.f, 0.f}};
  for (int m = 0; m < 64; ++m) {
    const float p0 = qs[ty * 4 + 0][m], p1 = qs[ty * 4 + 1][m];
    const float p2 = qs[ty * 4 + 2][m], p3 = qs[ty * 4 + 3][m];
    const float4 vv = *reinterpret_cast<const float4*>(&vs[m][tx * 4]);
    cacc[0][0] += p0 * vv.x; cacc[0][1] += p0 * vv.y; cacc[0][2] += p0 * vv.z; cacc[0][3] += p0 * vv.w;
    cacc[1][0] += p1 * vv.x; cacc[1][1] += p1 * vv.y; cacc[1][2] += p1 * vv.z; cacc[1][3] += p1 * vv.w;
    cacc[2][0] += p2 * vv.x; cacc[2][1] += p2 * vv.y; cacc[2][2] += p2 * vv.z; cacc[2][3] += p2 * vv.w;
    cacc[3][0] += p3 * vv.x; cacc[3][1] += p3 * vv.y; cacc[3][2] += p3 * vv.z; cacc[3][3] += p3 * vv.w;
  }

  float* ob = out + ((size_t)b * Tc + s * SPANc) * Dc + h * HDc;
#pragma unroll
  for (int i = 0; i < 4; ++i) {
    *reinterpret_cast<float4*>(ob + (size_t)(ty * 4 + i) * Dc + tx * 4) =
        make_float4(cacc[i][0], cacc[i][1], cacc[i][2], cacc[i][3]);
  }
}

// ---------------------------------------------------------------------------
extern "C" void kernel_launch(void* const* d_in, const int* in_sizes, int n_in,
                              void* d_out, int out_size, void* d_ws, size_t ws_size,
                              hipStream_t stream) {
  const float* x   = (const float*)d_in[0];
  const int*   msk = (const int*)d_in[1];
  const float* Wq  = (const float*)d_in[2];
  const float* Wk  = (const float*)d_in[3];
  const float* Wv  = (const float*)d_in[4];
  const float* w1  = (const float*)d_in[5];
  const float* b1  = (const float*)d_in[6];
  const float* w2  = (const float*)d_in[7];
  const float* b2  = (const float*)d_in[8];
  float* out = (float*)d_out;

  int*   eidx = (int*)d_ws;
  float* egw  = (float*)((char*)d_ws + (size_t)Bc * NSc * 2 * sizeof(int));

  gate_kernel<<<Bc * NSc, 256, 0, stream>>>(x, msk, w1, b1, w2, b2, eidx, egw);
  moe_attn_kernel<<<dim3(Hc, NSc, Bc), 256, 0, stream>>>(x, msk, Wq, Wk, Wv, eidx, egw, out);
}

// Round 3
// 721.951 us; speedup vs baseline: 3.5816x; 3.5816x over previous
//
#include <hip/hip_runtime.h>
#include <hip/hip_bf16.h>

// Problem constants (match reference)
constexpr int Bc = 4, Tc = 4096, Dc = 1024, Hc = 16, Ec = 8;
constexpr int SPANc = 64, NSc = 64, HDc = 64, GHc = 128;
#define FINF_MIN (-3.402823466e38f)

typedef __attribute__((ext_vector_type(8))) short short8;   // 8 bf16 (4 VGPRs)
typedef __attribute__((ext_vector_type(4))) float f32x4;

// ---------------------------------------------------------------------------
// Kernel 1: per-span gating (masked mean-pool -> MLP -> top-2 softmax)
// ---------------------------------------------------------------------------
__global__ __launch_bounds__(256) void gate_kernel(
    const float* __restrict__ x, const int* __restrict__ mask,
    const float* __restrict__ w1, const float* __restrict__ b1,
    const float* __restrict__ w2, const float* __restrict__ b2,
    int* __restrict__ eidx, float* __restrict__ egw)
{
  const int span = blockIdx.x;            // 0..255
  const int b = span / NSc, s = span % NSc;
  const int tid = threadIdx.x;

  __shared__ float mv[SPANc];
  __shared__ float msum_s;
  __shared__ float pooled[Dc];
  __shared__ float hbuf[GHc];
  __shared__ float logits[Ec];

  if (tid < SPANc) mv[tid] = (float)mask[(size_t)b * Tc + s * SPANc + tid];
  __syncthreads();
  if (tid == 0) {
    float ms = 0.f;
    for (int l = 0; l < SPANc; ++l) ms += mv[l];
    msum_s = fmaxf(ms, 1e-9f);
  }
  __syncthreads();

  {  // masked mean pool: each thread owns 4 columns
    const int c0 = tid * 4;
    float a0 = 0.f, a1 = 0.f, a2 = 0.f, a3 = 0.f;
    const float* xb = x + ((size_t)b * Tc + s * SPANc) * Dc + c0;
    for (int l = 0; l < SPANc; ++l) {
      const float m = mv[l];
      const float4 v = *reinterpret_cast<const float4*>(xb + (size_t)l * Dc);
      a0 += v.x * m; a1 += v.y * m; a2 += v.z * m; a3 += v.w * m;
    }
    const float inv = 1.f / msum_s;
    pooled[c0 + 0] = a0 * inv; pooled[c0 + 1] = a1 * inv;
    pooled[c0 + 2] = a2 * inv; pooled[c0 + 3] = a3 * inv;
  }
  __syncthreads();

  if (tid < GHc) {  // hidden layer
    const float* wr = w1 + (size_t)tid * Dc;
    float acc = b1[tid];
    for (int c = 0; c < Dc; c += 4) {
      const float4 w = *reinterpret_cast<const float4*>(wr + c);
      acc += pooled[c] * w.x + pooled[c + 1] * w.y + pooled[c + 2] * w.z + pooled[c + 3] * w.w;
    }
    hbuf[tid] = fmaxf(acc, 0.f);
  }
  __syncthreads();

  if (tid < Ec) {  // logits
    const float* wr = w2 + tid * GHc;
    float acc = b2[tid];
    for (int j = 0; j < GHc; ++j) acc += hbuf[j] * wr[j];
    logits[tid] = acc;
  }
  __syncthreads();

  if (tid == 0) {  // top-2 (ties -> lowest index, matching lax.top_k) + softmax
    int e0 = 0; float v0 = logits[0];
    for (int e = 1; e < Ec; ++e) { if (logits[e] > v0) { v0 = logits[e]; e0 = e; } }
    int e1 = (e0 == 0) ? 1 : 0; float v1 = logits[e1];
    for (int e = 0; e < Ec; ++e) {
      if (e == e0 || e == e1) continue;
      if (logits[e] > v1) { v1 = logits[e]; e1 = e; }
    }
    const float ex = expf(v1 - v0);               // v0 >= v1, stable
    const float den = 1.f + ex;
    eidx[span * 2 + 0] = e0; eidx[span * 2 + 1] = e1;
    egw[span * 2 + 0] = 1.f / den; egw[span * 2 + 1] = ex / den;
  }
}

// ---------------------------------------------------------------------------
// Kernel 2: fused per-(b, span, head) block with MFMA projections.
//   Projections via mfma_f32_16x16x32_bf16 with 3-term hi/lo split
//   (fp32-level accuracy). Attention in fp32 VALU (tiny FLOPs).
// LDS map (bytes):
//   [0,5120)      XH  bf16[64][40]  (x hi)      \
//   [5120,10240)  XL  bf16[64][40]  (x lo)       | staging, dead after GEMMs
//   [10240,15360) WH  bf16[64][40]  (W hi)       |
//   [15360,20480) WL  bf16[64][40]  (W lo)      /
//   [0,16384)     qs  f32[64][64]   (overlay; Q computed LAST)
//   [20480,36864) ks  f32[64][64]
//   [36864,53248) vs  f32[64][64]
// Row stride 40 bf16 = 80 B (odd multiple of 16 B) -> frag b128 reads ~2-way.
// ---------------------------------------------------------------------------
__global__ __launch_bounds__(256) void moe_attn_kernel(
    const float* __restrict__ x, const int* __restrict__ mask,
    const float* __restrict__ Wq, const float* __restrict__ Wk,
    const float* __restrict__ Wv,
    const int* __restrict__ eidx, const float* __restrict__ egw,
    float* __restrict__ out)
{
  const int h = blockIdx.x;
  const int s = blockIdx.y;
  const int b = blockIdx.z;
  const int span = b * NSc + s;
  const int tid = threadIdx.x;

  __shared__ __align__(16) char smem[53248];
  ushort* XH = (ushort*)(smem);
  ushort* XL = (ushort*)(smem + 5120);
  ushort* WHs = (ushort*)(smem + 10240);
  ushort* WLs = (ushort*)(smem + 15360);
  float* qs = (float*)(smem);
  float* ks = (float*)(smem + 20480);
  float* vs = (float*)(smem + 36864);

  const int e0 = eidx[span * 2 + 0];
  const int e1 = eidx[span * 2 + 1];
  const float g0 = egw[span * 2 + 0];
  const float g1 = egw[span * 2 + 1];

  const float* xb = x + ((size_t)b * Tc + s * SPANc) * Dc;  // 64 x 1024

  // staging assignment: row l = tid>>2 (0..63), k-quad kq = (tid&3)*8
  const int lrow = tid >> 2;
  const int kq = (tid & 3) * 8;
  const int stg_off = lrow * 40 + kq;          // ushort index into staging bufs

  // MFMA wave decomposition: wave w owns 32x32 quadrant (rbase, cbase)
  const int w = tid >> 6;
  const int lane = tid & 63;
  const int lr = lane & 15;
  const int koff = (lane >> 4) * 8;            // k element offset for frags
  const int rbase = (w >> 1) * 32;
  const int cbase = (w & 1) * 32;

  for (int p = 0; p < 3; ++p) {
    // order: V, K, Q  (Q last so qs can overlay staging)
    const float* Wp = (p == 0) ? Wv : (p == 1) ? Wk : Wq;
    const float* w0p = Wp + ((size_t)e0 * Dc + h * HDc + lrow) * Dc + kq;
    const float* w1p = Wp + ((size_t)e1 * Dc + h * HDc + lrow) * Dc + kq;
    const float* xp = xb + (size_t)lrow * Dc + kq;

    f32x4 acc[2][2];
#pragma unroll
    for (int mi = 0; mi < 2; ++mi)
#pragma unroll
      for (int ni = 0; ni < 2; ++ni)
#pragma unroll
        for (int j = 0; j < 4; ++j) acc[mi][ni][j] = 0.f;

    for (int t = 0; t < Dc / 32; ++t) {
      __syncthreads();  // previous step's frag reads complete
      {  // ---- stage x (hi/lo) ----
        const float4 va = *reinterpret_cast<const float4*>(xp);
        const float4 vb = *reinterpret_cast<const float4*>(xp + 4);
        float vv[8] = {va.x, va.y, va.z, va.w, vb.x, vb.y, vb.z, vb.w};
        uint hh[8], ll[8];
#pragma unroll
        for (int i = 0; i < 8; ++i) {
          const uint u = __float_as_uint(vv[i]);
          const uint hu = u & 0xffff0000u;
          hh[i] = hu;
          ll[i] = __float_as_uint(vv[i] - __uint_as_float(hu));
        }
        uint4 ph, pl;
        ph.x = (hh[0] >> 16) | hh[1]; ph.y = (hh[2] >> 16) | hh[3];
        ph.z = (hh[4] >> 16) | hh[5]; ph.w = (hh[6] >> 16) | hh[7];
        pl.x = (ll[0] >> 16) | (ll[1] & 0xffff0000u);
        pl.y = (ll[2] >> 16) | (ll[3] & 0xffff0000u);
        pl.z = (ll[4] >> 16) | (ll[5] & 0xffff0000u);
        pl.w = (ll[6] >> 16) | (ll[7] & 0xffff0000u);
        *reinterpret_cast<uint4*>(XH + stg_off) = ph;
        *reinterpret_cast<uint4*>(XL + stg_off) = pl;
      }
      {  // ---- stage combined W (hi/lo) ----
        const float4 a0 = *reinterpret_cast<const float4*>(w0p);
        const float4 a1 = *reinterpret_cast<const float4*>(w0p + 4);
        const float4 b0 = *reinterpret_cast<const float4*>(w1p);
        const float4 b1v = *reinterpret_cast<const float4*>(w1p + 4);
        float vv[8];
        vv[0] = g0 * a0.x + g1 * b0.x;  vv[1] = g0 * a0.y + g1 * b0.y;
        vv[2] = g0 * a0.z + g1 * b0.z;  vv[3] = g0 * a0.w + g1 * b0.w;
        vv[4] = g0 * a1.x + g1 * b1v.x; vv[5] = g0 * a1.y + g1 * b1v.y;
        vv[6] = g0 * a1.z + g1 * b1v.z; vv[7] = g0 * a1.w + g1 * b1v.w;
        uint hh[8], ll[8];
#pragma unroll
        for (int i = 0; i < 8; ++i) {
          const uint u = __float_as_uint(vv[i]);
          const uint hu = u & 0xffff0000u;
          hh[i] = hu;
          ll[i] = __float_as_uint(vv[i] - __uint_as_float(hu));
        }
        uint4 ph, pl;
        ph.x = (hh[0] >> 16) | hh[1]; ph.y = (hh[2] >> 16) | hh[3];
        ph.z = (hh[4] >> 16) | hh[5]; ph.w = (hh[6] >> 16) | hh[7];
        pl.x = (ll[0] >> 16) | (ll[1] & 0xffff0000u);
        pl.y = (ll[2] >> 16) | (ll[3] & 0xffff0000u);
        pl.z = (ll[4] >> 16) | (ll[5] & 0xffff0000u);
        pl.w = (ll[6] >> 16) | (ll[7] & 0xffff0000u);
        *reinterpret_cast<uint4*>(WHs + stg_off) = ph;
        *reinterpret_cast<uint4*>(WLs + stg_off) = pl;
      }
      xp += 32; w0p += 32; w1p += 32;
      __syncthreads();  // staging visible

      // ---- fragments + 12 MFMAs ----
      const short8 ah0 = *reinterpret_cast<const short8*>(XH + (rbase + lr) * 40 + koff);
      const short8 ah1 = *reinterpret_cast<const short8*>(XH + (rbase + 16 + lr) * 40 + koff);
      const short8 al0 = *reinterpret_cast<const short8*>(XL + (rbase + lr) * 40 + koff);
      const short8 al1 = *reinterpret_cast<const short8*>(XL + (rbase + 16 + lr) * 40 + koff);
      const short8 bh0 = *reinterpret_cast<const short8*>(WHs + (cbase + lr) * 40 + koff);
      const short8 bh1 = *reinterpret_cast<const short8*>(WHs + (cbase + 16 + lr) * 40 + koff);
      const short8 bl0 = *reinterpret_cast<const short8*>(WLs + (cbase + lr) * 40 + koff);
      const short8 bl1 = *reinterpret_cast<const short8*>(WLs + (cbase + 16 + lr) * 40 + koff);

      acc[0][0] = __builtin_amdgcn_mfma_f32_16x16x32_bf16(ah0, bh0, acc[0][0], 0, 0, 0);
      acc[0][1] = __builtin_amdgcn_mfma_f32_16x16x32_bf16(ah0, bh1, acc[0][1], 0, 0, 0);
      acc[1][0] = __builtin_amdgcn_mfma_f32_16x16x32_bf16(ah1, bh0, acc[1][0], 0, 0, 0);
      acc[1][1] = __builtin_amdgcn_mfma_f32_16x16x32_bf16(ah1, bh1, acc[1][1], 0, 0, 0);
      acc[0][0] = __builtin_amdgcn_mfma_f32_16x16x32_bf16(ah0, bl0, acc[0][0], 0, 0, 0);
      acc[0][1] = __builtin_amdgcn_mfma_f32_16x16x32_bf16(ah0, bl1, acc[0][1], 0, 0, 0);
      acc[1][0] = __builtin_amdgcn_mfma_f32_16x16x32_bf16(ah1, bl0, acc[1][0], 0, 0, 0);
      acc[1][1] = __builtin_amdgcn_mfma_f32_16x16x32_bf16(ah1, bl1, acc[1][1], 0, 0, 0);
      acc[0][0] = __builtin_amdgcn_mfma_f32_16x16x32_bf16(al0, bh0, acc[0][0], 0, 0, 0);
      acc[0][1] = __builtin_amdgcn_mfma_f32_16x16x32_bf16(al0, bh1, acc[0][1], 0, 0, 0);
      acc[1][0] = __builtin_amdgcn_mfma_f32_16x16x32_bf16(al1, bh0, acc[1][0], 0, 0, 0);
      acc[1][1] = __builtin_amdgcn_mfma_f32_16x16x32_bf16(al1, bh1, acc[1][1], 0, 0, 0);
    }

    // ---- epilogue: acc -> LDS (C/D layout: col=lane&15, row=(lane>>4)*4+reg) ----
    float* dst = (p == 0) ? vs : (p == 1) ? ks : qs;
    if (p == 2) __syncthreads();  // staging fully dead before qs overlay
#pragma unroll
    for (int mi = 0; mi < 2; ++mi)
#pragma unroll
      for (int ni = 0; ni < 2; ++ni) {
        const int col = cbase + ni * 16 + lr;
        const int row0 = rbase + mi * 16 + (lane >> 4) * 4;
#pragma unroll
        for (int j = 0; j < 4; ++j)
          dst[(row0 + j) * 64 + col] = acc[mi][ni][j];
      }
  }
  __syncthreads();  // Q/K/V complete

  // ---- scores = Q K^T / sqrt(hd), masked (fp32 VALU) ----
  const int tx = tid & 15;
  const int ty = tid >> 4;
  bool kvalid[4];
#pragma unroll
  for (int j = 0; j < 4; ++j)
    kvalid[j] = mask[(size_t)b * Tc + s * SPANc + tx * 4 + j] != 0;

  float sacc[4][4] = {{0.f, 0.f, 0.f, 0.f}, {0.f, 0.f, 0.f, 0.f},
                      {0.f, 0.f, 0.f, 0.f}, {0.f, 0.f, 0.f, 0.f}};
  for (int dd = 0; dd < 64; ++dd) {
    const int d = (dd + tid) & 63;   // staggered to avoid bank conflicts
    const float a0 = qs[(ty * 4 + 0) * 64 + d], a1 = qs[(ty * 4 + 1) * 64 + d];
    const float a2 = qs[(ty * 4 + 2) * 64 + d], a3 = qs[(ty * 4 + 3) * 64 + d];
    const float b0 = ks[(tx * 4 + 0) * 64 + d], b1v = ks[(tx * 4 + 1) * 64 + d];
    const float b2v = ks[(tx * 4 + 2) * 64 + d], b3 = ks[(tx * 4 + 3) * 64 + d];
    sacc[0][0] += a0 * b0; sacc[0][1] += a0 * b1v; sacc[0][2] += a0 * b2v; sacc[0][3] += a0 * b3;
    sacc[1][0] += a1 * b0; sacc[1][1] += a1 * b1v; sacc[1][2] += a1 * b2v; sacc[1][3] += a1 * b3;
    sacc[2][0] += a2 * b0; sacc[2][1] += a2 * b1v; sacc[2][2] += a2 * b2v; sacc[2][3] += a2 * b3;
    sacc[3][0] += a3 * b0; sacc[3][1] += a3 * b1v; sacc[3][2] += a3 * b2v; sacc[3][3] += a3 * b3;
  }
  __syncthreads();  // done reading qs; safe to overwrite with P
#pragma unroll
  for (int i = 0; i < 4; ++i)
#pragma unroll
    for (int j = 0; j < 4; ++j)
      qs[(ty * 4 + i) * 64 + tx * 4 + j] = kvalid[j] ? sacc[i][j] * 0.125f : FINF_MIN;
  __syncthreads();

  // ---- row softmax (first 64 lanes, staggered column order) ----
  if (tid < 64) {
    const int l = tid;
    float mx = FINF_MIN;
    for (int mm = 0; mm < 64; ++mm) {
      const int m = (mm + tid) & 63;
      mx = fmaxf(mx, qs[l * 64 + m]);
    }
    float sum = 0.f;
    for (int mm = 0; mm < 64; ++mm) {
      const int m = (mm + tid) & 63;
      const float e = expf(qs[l * 64 + m] - mx);
      qs[l * 64 + m] = e;
      sum += e;
    }
    const float inv = 1.f / sum;
    for (int mm = 0; mm < 64; ++mm) {
      const int m = (mm + tid) & 63;
      qs[l * 64 + m] *= inv;
    }
  }
  __syncthreads();

  // ---- ctx = P V ----
  float cacc[4][4] = {{0.f, 0.f, 0.f, 0.f}, {0.f, 0.f, 0.f, 0.f},
                      {0.f, 0.f, 0.f, 0.f}, {0.f, 0.f, 0.f, 0.f}};
  for (int m = 0; m < 64; ++m) {
    const float p0 = qs[(ty * 4 + 0) * 64 + m], p1 = qs[(ty * 4 + 1) * 64 + m];
    const float p2 = qs[(ty * 4 + 2) * 64 + m], p3 = qs[(ty * 4 + 3) * 64 + m];
    const float4 vv = *reinterpret_cast<const float4*>(&vs[m * 64 + tx * 4]);
    cacc[0][0] += p0 * vv.x; cacc[0][1] += p0 * vv.y; cacc[0][2] += p0 * vv.z; cacc[0][3] += p0 * vv.w;
    cacc[1][0] += p1 * vv.x; cacc[1][1] += p1 * vv.y; cacc[1][2] += p1 * vv.z; cacc[1][3] += p1 * vv.w;
    cacc[2][0] += p2 * vv.x; cacc[2][1] += p2 * vv.y; cacc[2][2] += p2 * vv.z; cacc[2][3] += p2 * vv.w;
    cacc[3][0] += p3 * vv.x; cacc[3][1] += p3 * vv.y; cacc[3][2] += p3 * vv.z; cacc[3][3] += p3 * vv.w;
  }

  float* ob = out + ((size_t)b * Tc + s * SPANc) * Dc + h * HDc;
#pragma unroll
  for (int i = 0; i < 4; ++i) {
    *reinterpret_cast<float4*>(ob + (size_t)(ty * 4 + i) * Dc + tx * 4) =
        make_float4(cacc[i][0], cacc[i][1], cacc[i][2], cacc[i][3]);
  }
}

// ---------------------------------------------------------------------------
extern "C" void kernel_launch(void* const* d_in, const int* in_sizes, int n_in,
                              void* d_out, int out_size, void* d_ws, size_t ws_size,
                              hipStream_t stream) {
  const float* x   = (const float*)d_in[0];
  const int*   msk = (const int*)d_in[1];
  const float* Wq  = (const float*)d_in[2];
  const float* Wk  = (const float*)d_in[3];
  const float* Wv  = (const float*)d_in[4];
  const float* w1  = (const float*)d_in[5];
  const float* b1  = (const float*)d_in[6];
  const float* w2  = (const float*)d_in[7];
  const float* b2  = (const float*)d_in[8];
  float* out = (float*)d_out;

  int*   eidx = (int*)d_ws;
  float* egw  = (float*)((char*)d_ws + (size_t)Bc * NSc * 2 * sizeof(int));

  gate_kernel<<<Bc * NSc, 256, 0, stream>>>(x, msk, w1, b1, w2, b2, eidx, egw);
  moe_attn_kernel<<<dim3(Hc, NSc, Bc), 256, 0, stream>>>(x, msk, Wq, Wk, Wv, eidx, egw, out);
}

// Round 4
// 690.112 us; speedup vs baseline: 3.7469x; 1.0461x over previous
//
#include <hip/hip_runtime.h>
#include <hip/hip_bf16.h>

// Problem constants (match reference)
constexpr int Bc = 4, Tc = 4096, Dc = 1024, Hc = 16, Ec = 8;
constexpr int SPANc = 64, NSc = 64, HDc = 64, GHc = 128;
#define FINF_MIN (-3.402823466e38f)

typedef __attribute__((ext_vector_type(8))) _Float16 half8;  // 8 fp16 (4 VGPRs)
typedef __attribute__((ext_vector_type(4))) float f32x4;

// ---------------------------------------------------------------------------
// Kernel 1: per-span gating (masked mean-pool -> MLP -> top-2 softmax)
// ---------------------------------------------------------------------------
__global__ __launch_bounds__(256) void gate_kernel(
    const float* __restrict__ x, const int* __restrict__ mask,
    const float* __restrict__ w1, const float* __restrict__ b1,
    const float* __restrict__ w2, const float* __restrict__ b2,
    int* __restrict__ eidx, float* __restrict__ egw)
{
  const int span = blockIdx.x;            // 0..255
  const int b = span / NSc, s = span % NSc;
  const int tid = threadIdx.x;

  __shared__ float mv[SPANc];
  __shared__ float msum_s;
  __shared__ float pooled[Dc];
  __shared__ float hbuf[GHc];
  __shared__ float logits[Ec];

  if (tid < SPANc) mv[tid] = (float)mask[(size_t)b * Tc + s * SPANc + tid];
  __syncthreads();
  if (tid == 0) {
    float ms = 0.f;
    for (int l = 0; l < SPANc; ++l) ms += mv[l];
    msum_s = fmaxf(ms, 1e-9f);
  }
  __syncthreads();

  {  // masked mean pool: each thread owns 4 columns
    const int c0 = tid * 4;
    float a0 = 0.f, a1 = 0.f, a2 = 0.f, a3 = 0.f;
    const float* xb = x + ((size_t)b * Tc + s * SPANc) * Dc + c0;
    for (int l = 0; l < SPANc; ++l) {
      const float m = mv[l];
      const float4 v = *reinterpret_cast<const float4*>(xb + (size_t)l * Dc);
      a0 += v.x * m; a1 += v.y * m; a2 += v.z * m; a3 += v.w * m;
    }
    const float inv = 1.f / msum_s;
    pooled[c0 + 0] = a0 * inv; pooled[c0 + 1] = a1 * inv;
    pooled[c0 + 2] = a2 * inv; pooled[c0 + 3] = a3 * inv;
  }
  __syncthreads();

  if (tid < GHc) {  // hidden layer
    const float* wr = w1 + (size_t)tid * Dc;
    float acc = b1[tid];
    for (int c = 0; c < Dc; c += 4) {
      const float4 w = *reinterpret_cast<const float4*>(wr + c);
      acc += pooled[c] * w.x + pooled[c + 1] * w.y + pooled[c + 2] * w.z + pooled[c + 3] * w.w;
    }
    hbuf[tid] = fmaxf(acc, 0.f);
  }
  __syncthreads();

  if (tid < Ec) {  // logits
    const float* wr = w2 + tid * GHc;
    float acc = b2[tid];
    for (int j = 0; j < GHc; ++j) acc += hbuf[j] * wr[j];
    logits[tid] = acc;
  }
  __syncthreads();

  if (tid == 0) {  // top-2 (ties -> lowest index, matching lax.top_k) + softmax
    int e0 = 0; float v0 = logits[0];
    for (int e = 1; e < Ec; ++e) { if (logits[e] > v0) { v0 = logits[e]; e0 = e; } }
    int e1 = (e0 == 0) ? 1 : 0; float v1 = logits[e1];
    for (int e = 0; e < Ec; ++e) {
      if (e == e0 || e == e1) continue;
      if (logits[e] > v1) { v1 = logits[e]; e1 = e; }
    }
    const float ex = expf(v1 - v0);               // v0 >= v1, stable
    const float den = 1.f + ex;
    eidx[span * 2 + 0] = e0; eidx[span * 2 + 1] = e1;
    egw[span * 2 + 0] = 1.f / den; egw[span * 2 + 1] = ex / den;
  }
}

// ---------------------------------------------------------------------------
// Kernel 2: fused per-(b, span, head) block, fp16 2-term MFMA projections.
//   Combined W scaled by 64 (folded into gate weights) then split hi/lo fp16:
//   y = (x_fp16 * wh + x_fp16 * wl) / 64  -> fp32-ish accuracy at 8 MFMA/step.
//   Register prefetch: global loads for step t+1 issued under MFMAs of t.
// LDS map (bytes), stride-68 f32 arrays to kill bank conflicts:
//   [0, 17408)     XF fp16[64][40] @0, WH @5120, WL @10240 ; qs f32[64][68] overlay
//   [17408, 34816) ks f32[64][68]
//   [34816, 52224) vs f32[64][68]
// ---------------------------------------------------------------------------
__global__ __launch_bounds__(256, 3) void moe_attn_kernel(
    const float* __restrict__ x, const int* __restrict__ mask,
    const float* __restrict__ Wq, const float* __restrict__ Wk,
    const float* __restrict__ Wv,
    const int* __restrict__ eidx, const float* __restrict__ egw,
    float* __restrict__ out)
{
  const int h = blockIdx.x;
  const int s = blockIdx.y;
  const int b = blockIdx.z;
  const int span = b * NSc + s;
  const int tid = threadIdx.x;

  __shared__ __align__(16) char smem[52224];
  _Float16* XF  = (_Float16*)(smem);
  _Float16* WHs = (_Float16*)(smem + 5120);
  _Float16* WLs = (_Float16*)(smem + 10240);
  float* qs = (float*)(smem);            // overlay (Q computed last)
  float* ks = (float*)(smem + 17408);
  float* vs = (float*)(smem + 34816);

  const int e0 = eidx[span * 2 + 0];
  const int e1 = eidx[span * 2 + 1];
  const float g0s = egw[span * 2 + 0] * 64.f;   // x64 scale keeps wl in fp16-normal range
  const float g1s = egw[span * 2 + 1] * 64.f;

  const float* xb = x + ((size_t)b * Tc + s * SPANc) * Dc;  // 64 x 1024

  // staging assignment: row l = tid>>2 (0..63), k-oct kq = (tid&3)*8
  const int lrow = tid >> 2;
  const int kq = (tid & 3) * 8;
  const int stg_off = lrow * 40 + kq;          // fp16-element index

  // MFMA wave decomposition: wave w owns 32x32 quadrant (rbase, cbase)
  const int w = tid >> 6;
  const int lane = tid & 63;
  const int lr = lane & 15;
  const int koff = (lane >> 4) * 8;            // k element offset for frags
  const int rbase = (w >> 1) * 32;
  const int cbase = (w & 1) * 32;

  const size_t woff0 = ((size_t)e0 * Dc + h * HDc + lrow) * Dc + kq;
  const size_t woff1 = ((size_t)e1 * Dc + h * HDc + lrow) * Dc + kq;

  // prefetch registers (step t+1 data loads while step t computes)
  const float* xcur  = xb + (size_t)lrow * Dc + kq;
  const float* w0cur = Wv + woff0;   // projection order: V, K, Q
  const float* w1cur = Wv + woff1;
  float4 rx0, rx1, ra0, ra1, rb0, rb1;
  rx0 = *reinterpret_cast<const float4*>(xcur);
  rx1 = *reinterpret_cast<const float4*>(xcur + 4);
  ra0 = *reinterpret_cast<const float4*>(w0cur);
  ra1 = *reinterpret_cast<const float4*>(w0cur + 4);
  rb0 = *reinterpret_cast<const float4*>(w1cur);
  rb1 = *reinterpret_cast<const float4*>(w1cur + 4);

  for (int p = 0; p < 3; ++p) {
    f32x4 acc[2][2];
#pragma unroll
    for (int mi = 0; mi < 2; ++mi)
#pragma unroll
      for (int ni = 0; ni < 2; ++ni)
#pragma unroll
        for (int j = 0; j < 4; ++j) acc[mi][ni][j] = 0.f;

    for (int t = 0; t < 32; ++t) {
      __syncthreads();  // previous step's frag reads complete
      {  // ---- stage x (single fp16) from regs ----
        half8 hx;
        hx[0] = (_Float16)rx0.x; hx[1] = (_Float16)rx0.y;
        hx[2] = (_Float16)rx0.z; hx[3] = (_Float16)rx0.w;
        hx[4] = (_Float16)rx1.x; hx[5] = (_Float16)rx1.y;
        hx[6] = (_Float16)rx1.z; hx[7] = (_Float16)rx1.w;
        *reinterpret_cast<half8*>(XF + stg_off) = hx;
      }
      {  // ---- stage combined W (hi/lo fp16) from regs ----
        float wv[8];
        wv[0] = g0s * ra0.x + g1s * rb0.x; wv[1] = g0s * ra0.y + g1s * rb0.y;
        wv[2] = g0s * ra0.z + g1s * rb0.z; wv[3] = g0s * ra0.w + g1s * rb0.w;
        wv[4] = g0s * ra1.x + g1s * rb1.x; wv[5] = g0s * ra1.y + g1s * rb1.y;
        wv[6] = g0s * ra1.z + g1s * rb1.z; wv[7] = g0s * ra1.w + g1s * rb1.w;
        half8 hw, lw;
#pragma unroll
        for (int i = 0; i < 8; ++i) {
          const _Float16 wh = (_Float16)wv[i];
          hw[i] = wh;
          lw[i] = (_Float16)(wv[i] - (float)wh);
        }
        *reinterpret_cast<half8*>(WHs + stg_off) = hw;
        *reinterpret_cast<half8*>(WLs + stg_off) = lw;
      }
      __syncthreads();  // staging visible

      // ---- issue next step's global loads (latency hides under MFMAs) ----
      if (!(p == 2 && t == 31)) {
        if (t < 31) {
          xcur += 32; w0cur += 32; w1cur += 32;
        } else {
          const float* Wn = (p == 0) ? Wk : Wq;
          xcur = xb + (size_t)lrow * Dc + kq;
          w0cur = Wn + woff0;
          w1cur = Wn + woff1;
        }
        rx0 = *reinterpret_cast<const float4*>(xcur);
        rx1 = *reinterpret_cast<const float4*>(xcur + 4);
        ra0 = *reinterpret_cast<const float4*>(w0cur);
        ra1 = *reinterpret_cast<const float4*>(w0cur + 4);
        rb0 = *reinterpret_cast<const float4*>(w1cur);
        rb1 = *reinterpret_cast<const float4*>(w1cur + 4);
      }

      // ---- fragments + 8 MFMAs ----
      const half8 a0  = *reinterpret_cast<const half8*>(XF  + (rbase + lr) * 40 + koff);
      const half8 a1  = *reinterpret_cast<const half8*>(XF  + (rbase + 16 + lr) * 40 + koff);
      const half8 bh0 = *reinterpret_cast<const half8*>(WHs + (cbase + lr) * 40 + koff);
      const half8 bh1 = *reinterpret_cast<const half8*>(WHs + (cbase + 16 + lr) * 40 + koff);
      const half8 bl0 = *reinterpret_cast<const half8*>(WLs + (cbase + lr) * 40 + koff);
      const half8 bl1 = *reinterpret_cast<const half8*>(WLs + (cbase + 16 + lr) * 40 + koff);

      acc[0][0] = __builtin_amdgcn_mfma_f32_16x16x32_f16(a0, bh0, acc[0][0], 0, 0, 0);
      acc[0][1] = __builtin_amdgcn_mfma_f32_16x16x32_f16(a0, bh1, acc[0][1], 0, 0, 0);
      acc[1][0] = __builtin_amdgcn_mfma_f32_16x16x32_f16(a1, bh0, acc[1][0], 0, 0, 0);
      acc[1][1] = __builtin_amdgcn_mfma_f32_16x16x32_f16(a1, bh1, acc[1][1], 0, 0, 0);
      acc[0][0] = __builtin_amdgcn_mfma_f32_16x16x32_f16(a0, bl0, acc[0][0], 0, 0, 0);
      acc[0][1] = __builtin_amdgcn_mfma_f32_16x16x32_f16(a0, bl1, acc[0][1], 0, 0, 0);
      acc[1][0] = __builtin_amdgcn_mfma_f32_16x16x32_f16(a1, bl0, acc[1][0], 0, 0, 0);
      acc[1][1] = __builtin_amdgcn_mfma_f32_16x16x32_f16(a1, bl1, acc[1][1], 0, 0, 0);
    }

    // ---- epilogue: acc/64 -> LDS (C/D: col=lane&15, row=(lane>>4)*4+reg) ----
    float* dst = (p == 0) ? vs : (p == 1) ? ks : qs;
    if (p == 2) __syncthreads();  // staging fully dead before qs overlay
#pragma unroll
    for (int mi = 0; mi < 2; ++mi)
#pragma unroll
      for (int ni = 0; ni < 2; ++ni) {
        const int col = cbase + ni * 16 + lr;
        const int row0 = rbase + mi * 16 + (lane >> 4) * 4;
#pragma unroll
        for (int j = 0; j < 4; ++j)
          dst[(row0 + j) * 68 + col] = acc[mi][ni][j] * 0.015625f;
      }
  }
  __syncthreads();  // Q/K/V complete

  // ---- scores = Q K^T / sqrt(hd), masked (fp32 VALU) ----
  const int tx = tid & 15;
  const int ty = tid >> 4;
  bool kvalid[4];
#pragma unroll
  for (int j = 0; j < 4; ++j)
    kvalid[j] = mask[(size_t)b * Tc + s * SPANc + tx * 4 + j] != 0;

  float sacc[4][4] = {{0.f, 0.f, 0.f, 0.f}, {0.f, 0.f, 0.f, 0.f},
                      {0.f, 0.f, 0.f, 0.f}, {0.f, 0.f, 0.f, 0.f}};
  for (int dd = 0; dd < 64; ++dd) {
    const int d = (dd + tid) & 63;   // staggered
    const float a0 = qs[(ty * 4 + 0) * 68 + d], a1 = qs[(ty * 4 + 1) * 68 + d];
    const float a2 = qs[(ty * 4 + 2) * 68 + d], a3 = qs[(ty * 4 + 3) * 68 + d];
    const float b0 = ks[(tx * 4 + 0) * 68 + d], b1v = ks[(tx * 4 + 1) * 68 + d];
    const float b2v = ks[(tx * 4 + 2) * 68 + d], b3 = ks[(tx * 4 + 3) * 68 + d];
    sacc[0][0] += a0 * b0; sacc[0][1] += a0 * b1v; sacc[0][2] += a0 * b2v; sacc[0][3] += a0 * b3;
    sacc[1][0] += a1 * b0; sacc[1][1] += a1 * b1v; sacc[1][2] += a1 * b2v; sacc[1][3] += a1 * b3;
    sacc[2][0] += a2 * b0; sacc[2][1] += a2 * b1v; sacc[2][2] += a2 * b2v; sacc[2][3] += a2 * b3;
    sacc[3][0] += a3 * b0; sacc[3][1] += a3 * b1v; sacc[3][2] += a3 * b2v; sacc[3][3] += a3 * b3;
  }
  __syncthreads();  // done reading qs; safe to overwrite with P
#pragma unroll
  for (int i = 0; i < 4; ++i)
#pragma unroll
    for (int j = 0; j < 4; ++j)
      qs[(ty * 4 + i) * 68 + tx * 4 + j] = kvalid[j] ? sacc[i][j] * 0.125f : FINF_MIN;
  __syncthreads();

  // ---- row softmax (first 64 lanes, staggered column order) ----
  if (tid < 64) {
    const int l = tid;
    float mx = FINF_MIN;
    for (int mm = 0; mm < 64; ++mm) {
      const int m = (mm + tid) & 63;
      mx = fmaxf(mx, qs[l * 68 + m]);
    }
    float sum = 0.f;
    for (int mm = 0; mm < 64; ++mm) {
      const int m = (mm + tid) & 63;
      const float e = expf(qs[l * 68 + m] - mx);
      qs[l * 68 + m] = e;
      sum += e;
    }
    const float inv = 1.f / sum;
    for (int mm = 0; mm < 64; ++mm) {
      const int m = (mm + tid) & 63;
      qs[l * 68 + m] *= inv;
    }
  }
  __syncthreads();

  // ---- ctx = P V ----
  float cacc[4][4] = {{0.f, 0.f, 0.f, 0.f}, {0.f, 0.f, 0.f, 0.f},
                      {0.f, 0.f, 0.f, 0.f}, {0.f, 0.f, 0.f, 0.f}};
  for (int m = 0; m < 64; ++m) {
    const float p0 = qs[(ty * 4 + 0) * 68 + m], p1 = qs[(ty * 4 + 1) * 68 + m];
    const float p2 = qs[(ty * 4 + 2) * 68 + m], p3 = qs[(ty * 4 + 3) * 68 + m];
    const float4 vv = *reinterpret_cast<const float4*>(&vs[m * 68 + tx * 4]);
    cacc[0][0] += p0 * vv.x; cacc[0][1] += p0 * vv.y; cacc[0][2] += p0 * vv.z; cacc[0][3] += p0 * vv.w;
    cacc[1][0] += p1 * vv.x; cacc[1][1] += p1 * vv.y; cacc[1][2] += p1 * vv.z; cacc[1][3] += p1 * vv.w;
    cacc[2][0] += p2 * vv.x; cacc[2][1] += p2 * vv.y; cacc[2][2] += p2 * vv.z; cacc[2][3] += p2 * vv.w;
    cacc[3][0] += p3 * vv.x; cacc[3][1] += p3 * vv.y; cacc[3][2] += p3 * vv.z; cacc[3][3] += p3 * vv.w;
  }

  float* ob = out + ((size_t)b * Tc + s * SPANc) * Dc + h * HDc;
#pragma unroll
  for (int i = 0; i < 4; ++i) {
    *reinterpret_cast<float4*>(ob + (size_t)(ty * 4 + i) * Dc + tx * 4) =
        make_float4(cacc[i][0], cacc[i][1], cacc[i][2], cacc[i][3]);
  }
}

// ---------------------------------------------------------------------------
extern "C" void kernel_launch(void* const* d_in, const int* in_sizes, int n_in,
                              void* d_out, int out_size, void* d_ws, size_t ws_size,
                              hipStream_t stream) {
  const float* x   = (const float*)d_in[0];
  const int*   msk = (const int*)d_in[1];
  const float* Wq  = (const float*)d_in[2];
  const float* Wk  = (const float*)d_in[3];
  const float* Wv  = (const float*)d_in[4];
  const float* w1  = (const float*)d_in[5];
  const float* b1  = (const float*)d_in[6];
  const float* w2  = (const float*)d_in[7];
  const float* b2  = (const float*)d_in[8];
  float* out = (float*)d_out;

  int*   eidx = (int*)d_ws;
  float* egw  = (float*)((char*)d_ws + (size_t)Bc * NSc * 2 * sizeof(int));

  gate_kernel<<<Bc * NSc, 256, 0, stream>>>(x, msk, w1, b1, w2, b2, eidx, egw);
  moe_attn_kernel<<<dim3(Hc, NSc, Bc), 256, 0, stream>>>(x, msk, Wq, Wk, Wv, eidx, egw, out);
}